// Round 1
// baseline (380.226 us; speedup 1.0000x reference)
//
#include <hip/hip_runtime.h>
#include <math.h>

#define N 8192
#define FIN 256
#define FOUT 64
#define LRELU_ALPHA 0.2f

#define R 16          // rows per block (kernel 2)
#define TJ 256        // j-tile
#define K2_THREADS 512

// Kernel 1: Wh = h @ W  (fp32), plus f_src/f_dst and exp tables.
// thread = (row-quad, feature). Lanes 0..63 = feature -> coalesced W reads,
// wave-uniform h reads (L1 broadcast). One wave handles 4 rows.
__global__ __launch_bounds__(256) void gat_prep(
    const float* __restrict__ h, const float* __restrict__ W, const float* __restrict__ a,
    float* __restrict__ Wh, float* __restrict__ fsrc, float* __restrict__ fdst,
    float* __restrict__ Ae, float* __restrict__ Be,
    float* __restrict__ Ce, float* __restrict__ De)
{
    const int t = threadIdx.x;
    const int f = t & 63;
    const int rq = (blockIdx.x * blockDim.x + t) >> 6;   // 0..N/4-1
    const int row0 = rq * 4;

    float acc[4] = {0.f, 0.f, 0.f, 0.f};
    for (int k0 = 0; k0 < FIN; k0 += 4) {
        const float w0 = W[(k0 + 0) * FOUT + f];
        const float w1 = W[(k0 + 1) * FOUT + f];
        const float w2 = W[(k0 + 2) * FOUT + f];
        const float w3 = W[(k0 + 3) * FOUT + f];
#pragma unroll
        for (int rr = 0; rr < 4; ++rr) {
            const float4 hv = *reinterpret_cast<const float4*>(
                &h[(size_t)(row0 + rr) * FIN + k0]);
            acc[rr] = fmaf(hv.x, w0, acc[rr]);
            acc[rr] = fmaf(hv.y, w1, acc[rr]);
            acc[rr] = fmaf(hv.z, w2, acc[rr]);
            acc[rr] = fmaf(hv.w, w3, acc[rr]);
        }
    }

    const float as = a[f];
    const float ad = a[FOUT + f];
#pragma unroll
    for (int rr = 0; rr < 4; ++rr) {
        const int row = row0 + rr;
        Wh[(size_t)row * FOUT + f] = acc[rr];
        float fs = acc[rr] * as;
        float fd = acc[rr] * ad;
#pragma unroll
        for (int off = 1; off < 64; off <<= 1) {
            fs += __shfl_xor(fs, off, 64);
            fd += __shfl_xor(fd, off, 64);
        }
        if (f == 0) {
            fsrc[row] = fs;
            Ae[row] = expf(fs);
            Ce[row] = expf(LRELU_ALPHA * fs);
            fdst[row] = fd;
            Be[row] = expf(fd);
            De[row] = expf(LRELU_ALPHA * fd);
        }
    }
}

// Kernel 2: flash-style masked softmax-PV.
// Block: 512 threads, R=16 rows, j-tiles of TJ=256.
// Phase 1: w -> LDS (coalesced adj reads; threads 0..255 rows 0..7, 256..511 rows 8..15)
// Phase 2: acc[r] (float4, feature quad) += w * Wh  (ds broadcast reads, conflict-free)
__global__ __launch_bounds__(K2_THREADS) void gat_main(
    const int* __restrict__ adj, const float* __restrict__ Wh,
    const float* __restrict__ fsrc, const float* __restrict__ fdst,
    const float* __restrict__ Ae, const float* __restrict__ Be,
    const float* __restrict__ Ce, const float* __restrict__ De,
    float* __restrict__ out)
{
    __shared__ float wlds[R][TJ];      // 16 KB
    __shared__ float zpart[8][8];
    __shared__ float Zfin[R];

    const int t = threadIdx.x;
    const int row0 = blockIdx.x * R;
    const int jcol = t & (TJ - 1);
    const int rhalf = t >> 8;          // 0 or 1

    float Ar[8], Cr[8], fsr[8];
#pragma unroll
    for (int rr = 0; rr < 8; ++rr) {
        const int row = row0 + rhalf * 8 + rr;
        Ar[rr] = Ae[row];
        Cr[rr] = Ce[row];
        fsr[rr] = fsrc[row];
    }

    const int fq = t & 15;             // feature quad 0..15
    const int sg = t >> 4;             // j subgroup 0..31

    float4 acc[R];
#pragma unroll
    for (int r = 0; r < R; ++r) acc[r] = make_float4(0.f, 0.f, 0.f, 0.f);
    float zacc[8] = {0.f, 0.f, 0.f, 0.f, 0.f, 0.f, 0.f, 0.f};

    for (int j0 = 0; j0 < N; j0 += TJ) {
        // ---- phase 1: compute w tile ----
        const float gj = fdst[j0 + jcol];
        const float Bj = Be[j0 + jcol];
        const float Dj = De[j0 + jcol];
#pragma unroll
        for (int rr = 0; rr < 8; ++rr) {
            const int r = rhalf * 8 + rr;
            const int adjv = adj[(size_t)(row0 + r) * N + j0 + jcol];
            float w = 0.f;
            if (adjv > 0)
                w = (fsr[rr] + gj > 0.f) ? Ar[rr] * Bj : Cr[rr] * Dj;
            zacc[rr] += w;
            wlds[r][jcol] = w;
        }
        __syncthreads();
        // ---- phase 2: FMA ----
#pragma unroll
        for (int jj = 0; jj < 8; ++jj) {
            const int j = sg * 8 + jj;
            const float4 wh = *reinterpret_cast<const float4*>(
                &Wh[(size_t)(j0 + j) * FOUT + fq * 4]);
#pragma unroll
            for (int r = 0; r < R; ++r) {
                const float wv = wlds[r][j];
                acc[r].x = fmaf(wv, wh.x, acc[r].x);
                acc[r].y = fmaf(wv, wh.y, acc[r].y);
                acc[r].z = fmaf(wv, wh.z, acc[r].z);
                acc[r].w = fmaf(wv, wh.w, acc[r].w);
            }
        }
        __syncthreads();
    }

    // ---- Z reduction ----
    const int lane = t & 63;
    const int wid = t >> 6;            // 0..7
#pragma unroll
    for (int rr = 0; rr < 8; ++rr) {
        float z = zacc[rr];
#pragma unroll
        for (int off = 1; off < 64; off <<= 1) z += __shfl_xor(z, off, 64);
        if (lane == 0) zpart[wid][rr] = z;
    }
    __syncthreads();
    if (t < R) {
        const int rh = t >> 3;
        const int rr = t & 7;
        Zfin[t] = zpart[rh * 4 + 0][rr] + zpart[rh * 4 + 1][rr] +
                  zpart[rh * 4 + 2][rr] + zpart[rh * 4 + 3][rr];
    }
    __syncthreads();

    // ---- acc reduction over 32 subgroups + epilogue ----
    float* red = &wlds[0][0];          // 4096 floats available, need 2048
#pragma unroll
    for (int r = 0; r < R; ++r) {
        *reinterpret_cast<float4*>(&red[t * 4]) = acc[r];
        __syncthreads();
        if (t < FOUT) {
            float s = 0.f;
#pragma unroll
            for (int g = 0; g < 32; ++g) s += red[g * 64 + t];
            const float hp = s / Zfin[r];
            out[(size_t)(row0 + r) * FOUT + t] = hp > 0.f ? hp : expm1f(hp);
        }
        __syncthreads();
    }
}

extern "C" void kernel_launch(void* const* d_in, const int* in_sizes, int n_in,
                              void* d_out, int out_size, void* d_ws, size_t ws_size,
                              hipStream_t stream) {
    const float* h   = (const float*)d_in[0];
    const int*   adj = (const int*)d_in[1];
    const float* W   = (const float*)d_in[2];
    const float* a   = (const float*)d_in[3];
    float* out = (float*)d_out;

    float* ws   = (float*)d_ws;
    float* Wh   = ws;                       // N*FOUT = 524288
    float* fsrc = Wh + (size_t)N * FOUT;    // 8192
    float* fdst = fsrc + N;
    float* Ae   = fdst + N;
    float* Be   = Ae + N;
    float* Ce   = Be + N;
    float* De   = Ce + N;                   // total ~2.29 MB

    gat_prep<<<dim3((N / 4) * 64 / 256), dim3(256), 0, stream>>>(
        h, W, a, Wh, fsrc, fdst, Ae, Be, Ce, De);
    gat_main<<<dim3(N / R), dim3(K2_THREADS), 0, stream>>>(
        adj, Wh, fsrc, fdst, Ae, Be, Ce, De, out);
}

// Round 2
// 199.097 us; speedup vs baseline: 1.9098x; 1.9098x over previous
//
#include <hip/hip_runtime.h>
#include <math.h>

#define N 8192
#define FIN 256
#define FOUT 64
#define LRELU_ALPHA 0.2f
#define LOG2E 1.442695040888963f

#define R 16          // rows per block (kernel 2)
#define TJ 256        // j-tile
#define NT (N / TJ)   // 32 tiles
#define K2_THREADS 512

// Kernel 1: Wh = h @ W  (fp32), plus f_src/f_dst.
__global__ __launch_bounds__(256) void gat_prep(
    const float* __restrict__ h, const float* __restrict__ W, const float* __restrict__ a,
    float* __restrict__ Wh, float* __restrict__ fsrc, float* __restrict__ fdst)
{
    const int t = threadIdx.x;
    const int f = t & 63;
    const int rq = (blockIdx.x * blockDim.x + t) >> 6;   // 0..N/4-1
    const int row0 = rq * 4;

    float acc[4] = {0.f, 0.f, 0.f, 0.f};
    for (int k0 = 0; k0 < FIN; k0 += 4) {
        const float w0 = W[(k0 + 0) * FOUT + f];
        const float w1 = W[(k0 + 1) * FOUT + f];
        const float w2 = W[(k0 + 2) * FOUT + f];
        const float w3 = W[(k0 + 3) * FOUT + f];
#pragma unroll
        for (int rr = 0; rr < 4; ++rr) {
            const float4 hv = *reinterpret_cast<const float4*>(
                &h[(size_t)(row0 + rr) * FIN + k0]);
            acc[rr] = fmaf(hv.x, w0, acc[rr]);
            acc[rr] = fmaf(hv.y, w1, acc[rr]);
            acc[rr] = fmaf(hv.z, w2, acc[rr]);
            acc[rr] = fmaf(hv.w, w3, acc[rr]);
        }
    }

    const float as = a[f];
    const float ad = a[FOUT + f];
#pragma unroll
    for (int rr = 0; rr < 4; ++rr) {
        const int row = row0 + rr;
        Wh[(size_t)row * FOUT + f] = acc[rr];
        float fs = acc[rr] * as;
        float fd = acc[rr] * ad;
#pragma unroll
        for (int off = 1; off < 64; off <<= 1) {
            fs += __shfl_xor(fs, off, 64);
            fd += __shfl_xor(fd, off, 64);
        }
        if (f == 0) {
            fsrc[row] = fs;
            fdst[row] = fd;
        }
    }
}

// Kernel 2: flash-style masked softmax-PV, pipelined.
// Phase-1 mapping: thread -> (row = t>>5, 8 j's at (t&31)*8); int4 adj loads.
// Phase-2 mapping: thread -> (fq = t&15 feature quad, sg = t>>4 j-subgroup of 8).
// Double-buffered w tile in LDS; 1 barrier per tile; adj/fdst prefetched to
// registers before the FMA phase so HBM latency hides under compute.
__global__ __launch_bounds__(K2_THREADS) void gat_main(
    const int* __restrict__ adj, const float* __restrict__ Wh,
    const float* __restrict__ fsrc, const float* __restrict__ fdst,
    float* __restrict__ out)
{
    __shared__ float wlds[2][R][TJ];   // 32 KB
    __shared__ float Zfin[R];

    const int t = threadIdx.x;
    const int row0 = blockIdx.x * R;

    // phase-1 (w-compute) mapping
    const int p1r = t >> 5;            // 0..15
    const int p1j = (t & 31) * 8;      // j offset in tile
    const float fsr = fsrc[row0 + p1r];
    const size_t adjrow = (size_t)(row0 + p1r) * N;

    // phase-2 (FMA) mapping
    const int fq = t & 15;
    const int sg = t >> 4;

    float4 acc[R];
#pragma unroll
    for (int r = 0; r < R; ++r) acc[r] = make_float4(0.f, 0.f, 0.f, 0.f);
    float zacc = 0.f;

#define WCALC(av, g, dst)                                        \
    {                                                            \
        float e_ = fsr + (g);                                    \
        float le_ = e_ > 0.f ? e_ : LRELU_ALPHA * e_;            \
        dst = ((av) > 0) ? __builtin_exp2f(le_ * LOG2E) : 0.f;   \
    }

    // ---- prologue: tile 0 w ----
    {
        const int4 a0 = *reinterpret_cast<const int4*>(&adj[adjrow + p1j]);
        const int4 a1 = *reinterpret_cast<const int4*>(&adj[adjrow + p1j + 4]);
        const float4 g0 = *reinterpret_cast<const float4*>(&fdst[p1j]);
        const float4 g1 = *reinterpret_cast<const float4*>(&fdst[p1j + 4]);
        float4 w0, w1;
        WCALC(a0.x, g0.x, w0.x); WCALC(a0.y, g0.y, w0.y);
        WCALC(a0.z, g0.z, w0.z); WCALC(a0.w, g0.w, w0.w);
        WCALC(a1.x, g1.x, w1.x); WCALC(a1.y, g1.y, w1.y);
        WCALC(a1.z, g1.z, w1.z); WCALC(a1.w, g1.w, w1.w);
        zacc += w0.x + w0.y + w0.z + w0.w + w1.x + w1.y + w1.z + w1.w;
        *reinterpret_cast<float4*>(&wlds[0][p1r][p1j]) = w0;
        *reinterpret_cast<float4*>(&wlds[0][p1r][p1j + 4]) = w1;
    }
    __syncthreads();

    int cur = 0;
    for (int tt = 0; tt < NT - 1; ++tt) {
        // ---- prefetch tile tt+1 (issued before FMA; latency hides) ----
        const int jb = (tt + 1) * TJ;
        const int4 a0 = *reinterpret_cast<const int4*>(&adj[adjrow + jb + p1j]);
        const int4 a1 = *reinterpret_cast<const int4*>(&adj[adjrow + jb + p1j + 4]);
        const float4 g0 = *reinterpret_cast<const float4*>(&fdst[jb + p1j]);
        const float4 g1 = *reinterpret_cast<const float4*>(&fdst[jb + p1j + 4]);

        // ---- FMA phase on buf[cur] ----
        const int jbase = tt * TJ;
#pragma unroll
        for (int jq = 0; jq < 2; ++jq) {
            const int j = sg * 8 + jq * 4;
            const float4 wh0 = *reinterpret_cast<const float4*>(
                &Wh[(size_t)(jbase + j + 0) * FOUT + fq * 4]);
            const float4 wh1 = *reinterpret_cast<const float4*>(
                &Wh[(size_t)(jbase + j + 1) * FOUT + fq * 4]);
            const float4 wh2 = *reinterpret_cast<const float4*>(
                &Wh[(size_t)(jbase + j + 2) * FOUT + fq * 4]);
            const float4 wh3 = *reinterpret_cast<const float4*>(
                &Wh[(size_t)(jbase + j + 3) * FOUT + fq * 4]);
#pragma unroll
            for (int r = 0; r < R; ++r) {
                const float4 wv = *reinterpret_cast<const float4*>(&wlds[cur][r][j]);
                acc[r].x = fmaf(wv.x, wh0.x, acc[r].x);
                acc[r].y = fmaf(wv.x, wh0.y, acc[r].y);
                acc[r].z = fmaf(wv.x, wh0.z, acc[r].z);
                acc[r].w = fmaf(wv.x, wh0.w, acc[r].w);
                acc[r].x = fmaf(wv.y, wh1.x, acc[r].x);
                acc[r].y = fmaf(wv.y, wh1.y, acc[r].y);
                acc[r].z = fmaf(wv.y, wh1.z, acc[r].z);
                acc[r].w = fmaf(wv.y, wh1.w, acc[r].w);
                acc[r].x = fmaf(wv.z, wh2.x, acc[r].x);
                acc[r].y = fmaf(wv.z, wh2.y, acc[r].y);
                acc[r].z = fmaf(wv.z, wh2.z, acc[r].z);
                acc[r].w = fmaf(wv.z, wh2.w, acc[r].w);
                acc[r].x = fmaf(wv.w, wh3.x, acc[r].x);
                acc[r].y = fmaf(wv.w, wh3.y, acc[r].y);
                acc[r].z = fmaf(wv.w, wh3.z, acc[r].z);
                acc[r].w = fmaf(wv.w, wh3.w, acc[r].w);
            }
        }

        // ---- compute w for tile tt+1, write other buffer ----
        {
            float4 w0, w1;
            WCALC(a0.x, g0.x, w0.x); WCALC(a0.y, g0.y, w0.y);
            WCALC(a0.z, g0.z, w0.z); WCALC(a0.w, g0.w, w0.w);
            WCALC(a1.x, g1.x, w1.x); WCALC(a1.y, g1.y, w1.y);
            WCALC(a1.z, g1.z, w1.z); WCALC(a1.w, g1.w, w1.w);
            zacc += w0.x + w0.y + w0.z + w0.w + w1.x + w1.y + w1.z + w1.w;
            *reinterpret_cast<float4*>(&wlds[cur ^ 1][p1r][p1j]) = w0;
            *reinterpret_cast<float4*>(&wlds[cur ^ 1][p1r][p1j + 4]) = w1;
        }
        __syncthreads();
        cur ^= 1;
    }

    // ---- last tile: FMA only ----
    {
        const int jbase = (NT - 1) * TJ;
#pragma unroll
        for (int jq = 0; jq < 2; ++jq) {
            const int j = sg * 8 + jq * 4;
            const float4 wh0 = *reinterpret_cast<const float4*>(
                &Wh[(size_t)(jbase + j + 0) * FOUT + fq * 4]);
            const float4 wh1 = *reinterpret_cast<const float4*>(
                &Wh[(size_t)(jbase + j + 1) * FOUT + fq * 4]);
            const float4 wh2 = *reinterpret_cast<const float4*>(
                &Wh[(size_t)(jbase + j + 2) * FOUT + fq * 4]);
            const float4 wh3 = *reinterpret_cast<const float4*>(
                &Wh[(size_t)(jbase + j + 3) * FOUT + fq * 4]);
#pragma unroll
            for (int r = 0; r < R; ++r) {
                const float4 wv = *reinterpret_cast<const float4*>(&wlds[cur][r][j]);
                acc[r].x = fmaf(wv.x, wh0.x, acc[r].x);
                acc[r].y = fmaf(wv.x, wh0.y, acc[r].y);
                acc[r].z = fmaf(wv.x, wh0.z, acc[r].z);
                acc[r].w = fmaf(wv.x, wh0.w, acc[r].w);
                acc[r].x = fmaf(wv.y, wh1.x, acc[r].x);
                acc[r].y = fmaf(wv.y, wh1.y, acc[r].y);
                acc[r].z = fmaf(wv.y, wh1.z, acc[r].z);
                acc[r].w = fmaf(wv.y, wh1.w, acc[r].w);
                acc[r].x = fmaf(wv.z, wh2.x, acc[r].x);
                acc[r].y = fmaf(wv.z, wh2.y, acc[r].y);
                acc[r].z = fmaf(wv.z, wh2.z, acc[r].z);
                acc[r].w = fmaf(wv.z, wh2.w, acc[r].w);
                acc[r].x = fmaf(wv.w, wh3.x, acc[r].x);
                acc[r].y = fmaf(wv.w, wh3.y, acc[r].y);
                acc[r].z = fmaf(wv.w, wh3.z, acc[r].z);
                acc[r].w = fmaf(wv.w, wh3.w, acc[r].w);
            }
        }
    }

    // ---- Z reduction: 32 threads per row (within 32-lane groups) ----
    {
        float z = zacc;
#pragma unroll
        for (int off = 1; off < 32; off <<= 1) z += __shfl_xor(z, off, 64);
        if ((t & 31) == 0) Zfin[p1r] = z;
    }
    __syncthreads();

    // ---- acc reduction over 32 subgroups + epilogue ----
    float* red = &wlds[0][0][0];       // 8 KB needed, 16 KB available
#pragma unroll
    for (int r = 0; r < R; ++r) {
        __syncthreads();
        *reinterpret_cast<float4*>(&red[t * 4]) = acc[r];
        __syncthreads();
        if (t < FOUT) {
            float s = 0.f;
#pragma unroll
            for (int g = 0; g < 32; ++g) s += red[g * 64 + t];
            const float hp = s / Zfin[r];
            out[(size_t)(row0 + r) * FOUT + t] = hp > 0.f ? hp : expm1f(hp);
        }
    }
}

extern "C" void kernel_launch(void* const* d_in, const int* in_sizes, int n_in,
                              void* d_out, int out_size, void* d_ws, size_t ws_size,
                              hipStream_t stream) {
    const float* h   = (const float*)d_in[0];
    const int*   adj = (const int*)d_in[1];
    const float* W   = (const float*)d_in[2];
    const float* a   = (const float*)d_in[3];
    float* out = (float*)d_out;

    float* ws   = (float*)d_ws;
    float* Wh   = ws;                       // N*FOUT
    float* fsrc = Wh + (size_t)N * FOUT;
    float* fdst = fsrc + N;

    gat_prep<<<dim3((N / 4) * 64 / 256), dim3(256), 0, stream>>>(
        h, W, a, Wh, fsrc, fdst);
    gat_main<<<dim3(N / R), dim3(K2_THREADS), 0, stream>>>(
        adj, Wh, fsrc, fdst, out);
}

// Round 3
// 193.293 us; speedup vs baseline: 1.9671x; 1.0300x over previous
//
#include <hip/hip_runtime.h>
#include <math.h>

#define N 8192
#define FIN 256
#define FOUT 64
#define ALPHA 0.2f
#define LOG2E 1.442695040888963f

typedef float f32x4 __attribute__((ext_vector_type(4)));
typedef short s16x8 __attribute__((ext_vector_type(8)));
typedef unsigned int u32x4 __attribute__((ext_vector_type(4)));

__device__ __forceinline__ unsigned pack_hi_pair(float w0, float w1) {
    // bf16(trunc) of w0 in low 16, w1 in high 16
    return (__float_as_uint(w0) >> 16) | (__float_as_uint(w1) & 0xffff0000u);
}
__device__ __forceinline__ float trunc_bf16(float w) {
    return __uint_as_float(__float_as_uint(w) & 0xffff0000u);
}
__device__ __forceinline__ s16x8 as_s16x8(u32x4 u) {
    union { u32x4 a; s16x8 b; } c; c.a = u; return c.b;
}
__device__ __forceinline__ float wcalc(int av, float fsr, float g) {
    float e = fsr + g;
    float le = e > 0.f ? e : ALPHA * e;
    float r = __builtin_exp2f(le * LOG2E);
    return av != 0 ? r : 0.f;
}

// ---------------- Kernel 1: Wh = h@W -> fsrc/fdst + WhT hi/lo (bf16, transposed) ----
__global__ __launch_bounds__(256) void gat_prep(
    const float* __restrict__ h, const float* __restrict__ W,
    const float* __restrict__ a,
    float* __restrict__ fsrc, float* __restrict__ fdst,
    unsigned short* __restrict__ WhT_hi, unsigned short* __restrict__ WhT_lo)
{
    __shared__ float sWh[16][FOUT + 1];
    const int t = threadIdx.x;
    const int f = t & 63;
    const int wq = t >> 6;                 // wave in block: 4 rows each
    const int row0 = blockIdx.x * 16;
    const int rbase = row0 + wq * 4;

    float acc[4] = {0.f, 0.f, 0.f, 0.f};
    for (int k0 = 0; k0 < FIN; k0 += 4) {
        const float w0 = W[(k0 + 0) * FOUT + f];
        const float w1 = W[(k0 + 1) * FOUT + f];
        const float w2 = W[(k0 + 2) * FOUT + f];
        const float w3 = W[(k0 + 3) * FOUT + f];
#pragma unroll
        for (int rr = 0; rr < 4; ++rr) {
            const float4 hv = *reinterpret_cast<const float4*>(
                &h[(size_t)(rbase + rr) * FIN + k0]);
            acc[rr] = fmaf(hv.x, w0, acc[rr]);
            acc[rr] = fmaf(hv.y, w1, acc[rr]);
            acc[rr] = fmaf(hv.z, w2, acc[rr]);
            acc[rr] = fmaf(hv.w, w3, acc[rr]);
        }
    }
    const float as = a[f], ad = a[FOUT + f];
#pragma unroll
    for (int rr = 0; rr < 4; ++rr) {
        sWh[wq * 4 + rr][f] = acc[rr];
        float fs = acc[rr] * as, fd = acc[rr] * ad;
#pragma unroll
        for (int off = 1; off < 64; off <<= 1) {
            fs += __shfl_xor(fs, off, 64);
            fd += __shfl_xor(fd, off, 64);
        }
        if (f == 0) { fsrc[rbase + rr] = fs; fdst[rbase + rr] = fd; }
    }
    __syncthreads();
    // transposed bf16 hi/lo: WhT[f][row]
    const int ff = t >> 2;                 // 0..63
    const int r4 = (t & 3) * 4;            // 0,4,8,12
    const float w0 = sWh[r4 + 0][ff], w1 = sWh[r4 + 1][ff];
    const float w2 = sWh[r4 + 2][ff], w3 = sWh[r4 + 3][ff];
    uint2 hv2, lv2;
    hv2.x = pack_hi_pair(w0, w1);
    hv2.y = pack_hi_pair(w2, w3);
    lv2.x = pack_hi_pair(w0 - trunc_bf16(w0), w1 - trunc_bf16(w1));
    lv2.y = pack_hi_pair(w2 - trunc_bf16(w2), w3 - trunc_bf16(w3));
    *reinterpret_cast<uint2*>(&WhT_hi[(size_t)ff * N + row0 + r4]) = hv2;
    *reinterpret_cast<uint2*>(&WhT_lo[(size_t)ff * N + row0 + r4]) = lv2;
}

// ---------------- Kernel 2: MFMA flash softmax-PV, no main-loop LDS/barriers ----
// Block: 512 thr = 8 waves, 16 rows shared; wave w owns j in [w*1024,(w+1)*1024).
// Lane l: A row = l&15, k-slot j = base + (l>>4)*8 + e. Same k-map for B frags
// (WhT contiguous) => any K-permutation assumption cancels in A.B.
__global__ __launch_bounds__(512, 4) void gat_main(
    const int* __restrict__ adj,
    const unsigned short* __restrict__ WhT_hi,
    const unsigned short* __restrict__ WhT_lo,
    const float* __restrict__ fsrc, const float* __restrict__ fdst,
    float* __restrict__ out)
{
    __shared__ float accbuf[8][4][64][4];  // 32 KB
    __shared__ float zbuf[8][16];
    __shared__ float Zfin[16];

    const int t = threadIdx.x;
    const int l = t & 63;
    const int w = t >> 6;
    const int row0 = blockIdx.x * 16;
    const int r = l & 15;
    const int kg8 = (l >> 4) << 3;
    const int jwbase = w * 1024;
    const float fsr = fsrc[row0 + r];
    const size_t adjrow = (size_t)(row0 + r) * N;

    f32x4 acc0 = {0.f, 0.f, 0.f, 0.f};
    f32x4 acc1 = {0.f, 0.f, 0.f, 0.f};
    f32x4 acc2 = {0.f, 0.f, 0.f, 0.f};
    f32x4 acc3 = {0.f, 0.f, 0.f, 0.f};
    float zacc = 0.f;

#define LOADK(kk, A0, A1, G0, G1)                                              \
    {                                                                          \
        const int jl_ = jwbase + (kk) * 32 + kg8;                              \
        A0 = *reinterpret_cast<const int4*>(&adj[adjrow + jl_]);               \
        A1 = *reinterpret_cast<const int4*>(&adj[adjrow + jl_ + 4]);           \
        G0 = *reinterpret_cast<const float4*>(&fdst[jl_]);                     \
        G1 = *reinterpret_cast<const float4*>(&fdst[jl_ + 4]);                 \
    }

#define COMPUTEK(kk, A0, A1, G0, G1)                                           \
    {                                                                          \
        const size_t bo_ = (size_t)r * N + (jwbase + (kk) * 32 + kg8);         \
        const s16x8 bh0 = *reinterpret_cast<const s16x8*>(&WhT_hi[bo_]);       \
        const s16x8 bh1 = *reinterpret_cast<const s16x8*>(&WhT_hi[bo_ + 16*N]);\
        const s16x8 bh2 = *reinterpret_cast<const s16x8*>(&WhT_hi[bo_ + 32*N]);\
        const s16x8 bh3 = *reinterpret_cast<const s16x8*>(&WhT_hi[bo_ + 48*N]);\
        const s16x8 bl0 = *reinterpret_cast<const s16x8*>(&WhT_lo[bo_]);       \
        const s16x8 bl1 = *reinterpret_cast<const s16x8*>(&WhT_lo[bo_ + 16*N]);\
        const s16x8 bl2 = *reinterpret_cast<const s16x8*>(&WhT_lo[bo_ + 32*N]);\
        const s16x8 bl3 = *reinterpret_cast<const s16x8*>(&WhT_lo[bo_ + 48*N]);\
        const float w0 = wcalc(A0.x, fsr, G0.x), w1 = wcalc(A0.y, fsr, G0.y);  \
        const float w2 = wcalc(A0.z, fsr, G0.z), w3 = wcalc(A0.w, fsr, G0.w);  \
        const float w4 = wcalc(A1.x, fsr, G1.x), w5 = wcalc(A1.y, fsr, G1.y);  \
        const float w6 = wcalc(A1.z, fsr, G1.z), w7 = wcalc(A1.w, fsr, G1.w);  \
        zacc += (w0 + w1) + (w2 + w3) + ((w4 + w5) + (w6 + w7));               \
        u32x4 hu_, lu_;                                                        \
        hu_.x = pack_hi_pair(w0, w1); hu_.y = pack_hi_pair(w2, w3);            \
        hu_.z = pack_hi_pair(w4, w5); hu_.w = pack_hi_pair(w6, w7);            \
        lu_.x = pack_hi_pair(w0 - trunc_bf16(w0), w1 - trunc_bf16(w1));        \
        lu_.y = pack_hi_pair(w2 - trunc_bf16(w2), w3 - trunc_bf16(w3));        \
        lu_.z = pack_hi_pair(w4 - trunc_bf16(w4), w5 - trunc_bf16(w5));        \
        lu_.w = pack_hi_pair(w6 - trunc_bf16(w6), w7 - trunc_bf16(w7));        \
        const s16x8 ah = as_s16x8(hu_), al = as_s16x8(lu_);                    \
        acc0 = __builtin_amdgcn_mfma_f32_16x16x32_bf16(ah, bh0, acc0, 0, 0, 0);\
        acc1 = __builtin_amdgcn_mfma_f32_16x16x32_bf16(ah, bh1, acc1, 0, 0, 0);\
        acc2 = __builtin_amdgcn_mfma_f32_16x16x32_bf16(ah, bh2, acc2, 0, 0, 0);\
        acc3 = __builtin_amdgcn_mfma_f32_16x16x32_bf16(ah, bh3, acc3, 0, 0, 0);\
        acc0 = __builtin_amdgcn_mfma_f32_16x16x32_bf16(ah, bl0, acc0, 0, 0, 0);\
        acc1 = __builtin_amdgcn_mfma_f32_16x16x32_bf16(ah, bl1, acc1, 0, 0, 0);\
        acc2 = __builtin_amdgcn_mfma_f32_16x16x32_bf16(ah, bl2, acc2, 0, 0, 0);\
        acc3 = __builtin_amdgcn_mfma_f32_16x16x32_bf16(ah, bl3, acc3, 0, 0, 0);\
        acc0 = __builtin_amdgcn_mfma_f32_16x16x32_bf16(al, bh0, acc0, 0, 0, 0);\
        acc1 = __builtin_amdgcn_mfma_f32_16x16x32_bf16(al, bh1, acc1, 0, 0, 0);\
        acc2 = __builtin_amdgcn_mfma_f32_16x16x32_bf16(al, bh2, acc2, 0, 0, 0);\
        acc3 = __builtin_amdgcn_mfma_f32_16x16x32_bf16(al, bh3, acc3, 0, 0, 0);\
    }

    int4 a0A, a1A; float4 g0A, g1A;
    int4 a0B, a1B; float4 g0B, g1B;
    LOADK(0, a0A, a1A, g0A, g1A);
    for (int kk = 0; kk < 32; kk += 2) {
        LOADK(kk + 1, a0B, a1B, g0B, g1B);
        COMPUTEK(kk, a0A, a1A, g0A, g1A);
        if (kk + 2 < 32) LOADK(kk + 2, a0A, a1A, g0A, g1A);
        COMPUTEK(kk + 1, a0B, a1B, g0B, g1B);
    }
#undef LOADK
#undef COMPUTEK

    // ---- cross-wave reduction ----
    zacc += __shfl_xor(zacc, 16, 64);
    zacc += __shfl_xor(zacc, 32, 64);
    if (l < 16) zbuf[w][l] = zacc;
    *reinterpret_cast<f32x4*>(&accbuf[w][0][l][0]) = acc0;
    *reinterpret_cast<f32x4*>(&accbuf[w][1][l][0]) = acc1;
    *reinterpret_cast<f32x4*>(&accbuf[w][2][l][0]) = acc2;
    *reinterpret_cast<f32x4*>(&accbuf[w][3][l][0]) = acc3;
    __syncthreads();
    if (t < 16) {
        float z = 0.f;
#pragma unroll
        for (int w2 = 0; w2 < 8; ++w2) z += zbuf[w2][t];
        Zfin[t] = z;
    }
    __syncthreads();

    // D layout (verified): col = lane&15, row = (lane>>4)*4 + reg
#pragma unroll
    for (int e0 = 0; e0 < 2; ++e0) {
        const int e = t + e0 * 512;
        const int rr = e >> 6, f2 = e & 63;
        const int c = f2 >> 4;
        const int ln = (f2 & 15) | ((rr >> 2) << 4);
        const int rg = rr & 3;
        float s = 0.f;
#pragma unroll
        for (int w2 = 0; w2 < 8; ++w2) s += accbuf[w2][c][ln][rg];
        const float hp = s / Zfin[rr];
        out[(size_t)(row0 + rr) * FOUT + f2] = hp > 0.f ? hp : expm1f(hp);
    }
}

extern "C" void kernel_launch(void* const* d_in, const int* in_sizes, int n_in,
                              void* d_out, int out_size, void* d_ws, size_t ws_size,
                              hipStream_t stream) {
    const float* h   = (const float*)d_in[0];
    const int*   adj = (const int*)d_in[1];
    const float* W   = (const float*)d_in[2];
    const float* a   = (const float*)d_in[3];
    float* out = (float*)d_out;

    float* ws = (float*)d_ws;
    float* fsrc = ws;
    float* fdst = fsrc + N;
    unsigned short* WhT_hi = (unsigned short*)(fdst + N);
    unsigned short* WhT_lo = WhT_hi + (size_t)FOUT * N;

    gat_prep<<<dim3(N / 16), dim3(256), 0, stream>>>(
        h, W, a, fsrc, fdst, WhT_hi, WhT_lo);
    gat_main<<<dim3(N / 16), dim3(512), 0, stream>>>(
        adj, WhT_hi, WhT_lo, fsrc, fdst, out);
}